// Round 11
// baseline (214.012 us; speedup 1.0000x reference)
//
#include <hip/hip_runtime.h>
#include <hip/hip_bf16.h>
#include <stdint.h>

// ---------- types ----------
typedef __attribute__((ext_vector_type(8))) short short8;   // 8 x bf16 (raw)
typedef __attribute__((ext_vector_type(4))) float f32x4;

typedef const __attribute__((address_space(1))) void gv_t;
typedef __attribute__((address_space(3))) void lv_t;

#define SCQ 0.18033688011112042f   // log2(e)/sqrt(64), folded into Q projection

__device__ __forceinline__ void gl_lds16(const void* g, void* l) {
    // async global->LDS, 16B per lane; LDS dest must be waveBase + lane*16
    __builtin_amdgcn_global_load_lds((gv_t*)g, (lv_t*)l, 16, 0, 0);
}

__device__ __forceinline__ unsigned short f2bf(float f) {
    union { float f; unsigned int u; } v; v.f = f;
    unsigned int r = v.u + 0x7fffu + ((v.u >> 16) & 1u);   // RNE
    return (unsigned short)(r >> 16);
}

__device__ __forceinline__ float bf2f(unsigned short u) {
    union { unsigned int i; float f; } v; v.i = ((unsigned int)u) << 16; return v.f;
}

__device__ __forceinline__ unsigned int pack2bf(float a, float b) {
    union { __hip_bfloat162 h2; unsigned int u; } cv;
    cv.h2 = __float22bfloat162_rn(make_float2(a, b));   // v_cvt_pk_bf16_f32 on gfx950
    return cv.u;                                        // low = a, high = b
}

__device__ __forceinline__ f32x4 zero4() { f32x4 z = {0.f, 0.f, 0.f, 0.f}; return z; }

// ---------- fused prep: LoRA weight fold (Wqkv & Wmsa) + y->bf16 cvt ----------
__global__ void k_prep(const float* __restrict__ y,
                       const float* __restrict__ Wqkv, const float* __restrict__ Wmsa,
                       const float* __restrict__ Bq, const float* __restrict__ Aq,
                       const float* __restrict__ Bk, const float* __restrict__ Ak,
                       const float* __restrict__ Bv, const float* __restrict__ Av,
                       const float* __restrict__ Bo, const float* __restrict__ Ao,
                       unsigned short* __restrict__ wout, unsigned short* __restrict__ yb) {
    const int bid = blockIdx.x;
    if (bid < 16384) {
        int idx = bid * 256 + threadIdx.x;     // n*1024 + k, n in [0,4096)
        int n = idx >> 10, k = idx & 1023;
        int sel = n >> 10, n0 = n & 1023;
        const float* Bp = (sel == 0) ? Bq : (sel == 1) ? Bk : (sel == 2) ? Bv : Bo;
        const float* Ap = (sel == 0) ? Aq : (sel == 1) ? Ak : (sel == 2) ? Av : Ao;
        float acc = (sel < 3) ? Wqkv[idx] : Wmsa[idx - 3145728];
        // B row is 8 contiguous floats -> 2x float4 (was 8 scalar loads)
        float4 b0 = *(const float4*)(Bp + k * 8);
        float4 b1 = *(const float4*)(Bp + k * 8 + 4);
        acc += b0.x * Ap[0 * 1024 + n0] + b0.y * Ap[1 * 1024 + n0]
             + b0.z * Ap[2 * 1024 + n0] + b0.w * Ap[3 * 1024 + n0]
             + b1.x * Ap[4 * 1024 + n0] + b1.y * Ap[5 * 1024 + n0]
             + b1.z * Ap[6 * 1024 + n0] + b1.w * Ap[7 * 1024 + n0];
        wout[idx] = f2bf(acc * ((sel == 0) ? SCQ : 1.0f));
    } else {
        int i = ((bid - 16384) * 256 + threadIdx.x) * 4;
        float4 v = *(const float4*)(y + i);
        union { unsigned short u[4]; uint2 w; } o;
        o.u[0] = f2bf(v.x); o.u[1] = f2bf(v.y); o.u[2] = f2bf(v.z); o.u[3] = f2bf(v.w);
        *(uint2*)(yb + i) = o.w;
    }
}

// ---------- GEMM: C[M,N] = A[M,K](bf16) @ B[N,K]^T(bf16), dbuf cross-barrier prefetch ----------
// EPI=0: bf16(acc+bias[col]); cols<1024 get SCQ on bias; cols>=2048 (V) are written
//        TRANSPOSED into vtg[b,h][d][tok] via LDS -> coalesced 128B global stores.
// EPI=2: bf16(acc) partial into Cout + split*4096*1024  (K-split x2; k_ln combines).
// XMAP=1 (gemm1): each XCD owns an 8y x 12x group. XMAP=2 (gemm2 K-split).
template <int TM, int EPI, int MINW, int XMAP>
__global__ __launch_bounds__(256, MINW) void k_gemm(const unsigned short* __restrict__ Ag,
                                                    const unsigned short* __restrict__ Bg,
                                                    const float* __restrict__ bias,
                                                    const float* __restrict__ yres,
                                                    unsigned short* __restrict__ vtg,
                                                    void* __restrict__ Cout,
                                                    int M, int N, int K, int Kst) {
    constexpr int WAVES_N = 256 / TM;
    constexpr int WN = TM / 2;
    constexpr int NI = WN / 16;
    constexpr int ACALLS = TM / 64;
    constexpr int ASZ = 2 * TM * 32;               // shorts
    __shared__ unsigned short SH[ASZ + 2 * 128 * 32];
    unsigned short* As0 = SH;                      // [2][TM*32]
    unsigned short* Bs0 = SH + ASZ;                // [2][128*32]
    const int flat = threadIdx.x;
    int m0, n0, koff = 0, split = 0;
    if constexpr (XMAP == 1) {                     // 24 x-blocks, 32 y-blocks
        int id = blockIdx.x, xcd = id & 7, j = id >> 3;
        int yy = (xcd & 3) * 8 + j / 12;
        int xx = (xcd >> 2) * 12 + j % 12;
        m0 = yy * TM; n0 = xx * 128;
    } else if constexpr (XMAP == 2) {              // K-split x2: 8 x-blocks, 32 y-blocks, 2 splits
        int id = blockIdx.x, xcd = id & 7, j = id >> 3;   // j in [0,64)
        split = xcd >> 2;
        int yy = (xcd & 3) * 8 + (j >> 3);         // [0,32)
        int xx = j & 7;                            // [0,8)
        m0 = yy * TM; n0 = xx * 128; koff = split * 512;
    } else {
        m0 = blockIdx.y * TM; n0 = blockIdx.x * 128;
    }
    const int lane = flat & 63, wave = flat >> 6;
    const int l16 = lane & 15, quad = lane >> 4;
    const int wm = (wave / WAVES_N) * 64, wn = (wave % WAVES_N) * WN;

    f32x4 acc[4][NI];
    #pragma unroll
    for (int mi = 0; mi < 4; ++mi)
        #pragma unroll
        for (int ni = 0; ni < NI; ++ni) acc[mi][ni] = zero4();

    const unsigned short* ap = Ag + (size_t)(m0 + (flat >> 2)) * Kst + koff + (flat & 3) * 8;
    const unsigned short* bp = Bg + (size_t)(n0 + (flat >> 2)) * Kst + koff + (flat & 3) * 8;
    const size_t rstep = (size_t)64 * Kst;

    #pragma unroll
    for (int c = 0; c < ACALLS; ++c) gl_lds16(ap + c * rstep, &As0[c * 2048 + flat * 8]);
    gl_lds16(bp,         &Bs0[flat * 8]);
    gl_lds16(bp + rstep, &Bs0[2048 + flat * 8]);
    ap += 32; bp += 32;
    __syncthreads();

    for (int k0 = 0; k0 < K; k0 += 32) {
        const int cur = (k0 >> 5) & 1;
        if (k0 + 32 < K) {
            const int nxt = cur ^ 1;
            #pragma unroll
            for (int c = 0; c < ACALLS; ++c) gl_lds16(ap + c * rstep, &As0[nxt * TM * 32 + c * 2048 + flat * 8]);
            gl_lds16(bp,         &Bs0[nxt * 4096 + flat * 8]);
            gl_lds16(bp + rstep, &Bs0[nxt * 4096 + 2048 + flat * 8]);
            ap += 32; bp += 32;
        }

        short8 af[4], bfr[NI];
        #pragma unroll
        for (int i = 0; i < 4; ++i) af[i] = *(const short8*)&As0[cur * TM * 32 + (wm + i * 16 + l16) * 32 + quad * 8];
        #pragma unroll
        for (int i = 0; i < NI; ++i) bfr[i] = *(const short8*)&Bs0[cur * 4096 + (wn + i * 16 + l16) * 32 + quad * 8];
        #pragma unroll
        for (int mi = 0; mi < 4; ++mi)
            #pragma unroll
            for (int ni = 0; ni < NI; ++ni)
                acc[mi][ni] = __builtin_amdgcn_mfma_f32_16x16x32_bf16(af[mi], bfr[ni], acc[mi][ni], 0, 0, 0);

        __syncthreads();
    }

    // epilogue: C/D layout col=lane&15, row=quad*4+reg
    if constexpr (EPI == 0) {
        unsigned short* C = (unsigned short*)Cout;
        if (n0 < 2048) {      // Q/K columns: normal row-major bf16 store
            #pragma unroll
            for (int ni = 0; ni < NI; ++ni) {
                int col = n0 + wn + ni * 16 + l16;
                float bv = bias[col] * ((col < 1024) ? SCQ : 1.0f);
                #pragma unroll
                for (int mi = 0; mi < 4; ++mi) {
                    int row = m0 + wm + mi * 16 + quad * 4;
                    #pragma unroll
                    for (int r = 0; r < 4; ++r)
                        C[(size_t)(row + r) * N + col] = f2bf(acc[mi][ni][r] + bv);
                }
            }
        } else {              // V columns: LDS transpose -> coalesced vtg[(b,h,d)][tok] stores
            if constexpr (TM == 128) {
                #pragma unroll
                for (int ni = 0; ni < NI; ++ni) {
                    int c = wn + ni * 16 + l16;
                    float bv = bias[n0 + c];
                    int sw = (c & 7) << 3;
                    #pragma unroll
                    for (int mi = 0; mi < 4; ++mi) {
                        int row = wm + mi * 16 + quad * 4;
                        uint2 w;
                        w.x = pack2bf(acc[mi][ni][0] + bv, acc[mi][ni][1] + bv);
                        w.y = pack2bf(acc[mi][ni][2] + bv, acc[mi][ni][3] + bv);
                        *(uint2*)&SH[c * 128 + (row ^ sw)] = w;
                    }
                }
                __syncthreads();
                const int bb = m0 >> 11, ss = m0 & 2047;
                #pragma unroll
                for (int p = 0; p < 4; ++p) {
                    int c = p * 32 + (flat >> 3);
                    int col = n0 + c;
                    int hh = (col - 2048) >> 6, dd = col & 63;
                    unsigned short* dst = vtg + (size_t)(hh * 64 + dd) * 2048
                                              + (size_t)bb * 2097152 + ss;
                    int sw = (c & 7) << 3;
                    #pragma unroll
                    for (int hf = 0; hf < 2; ++hf) {
                        int off = hf * 64 + (flat & 7) * 8;
                        uint4 v = *(const uint4*)&SH[c * 128 + (off ^ sw)];
                        *(uint4*)(dst + off) = v;
                    }
                }
            }
        }
    } else {   // EPI == 2: bf16 K-split partial
        unsigned short* C = (unsigned short*)Cout + (size_t)split * 4194304;   // 4096*1024
        #pragma unroll
        for (int ni = 0; ni < NI; ++ni) {
            int col = n0 + wn + ni * 16 + l16;
            #pragma unroll
            for (int mi = 0; mi < 4; ++mi) {
                int row = m0 + wm + mi * 16 + quad * 4;
                #pragma unroll
                for (int r = 0; r < 4; ++r)
                    C[(size_t)(row + r) * N + col] = f2bf(acc[mi][ni][r]);
            }
        }
    }
}

// ---------- fused flash attention (q-tile 128, 2 waves x 64 q/wave, KV-split x2) ----------
// The missing cell of the attn 2x2 matrix: 64 q/wave (r4's LDS-relief: 16 b128
// reads serve 72 MFMA) AND 4 blocks/CU (r3's barrier-coverage) at 2 waves/SIMD.
// 128-thread blocks, grid 1024 = 4 blocks/CU x 2 waves = 2 waves/SIMD (NOT r1's
// 1-wave/SIMD regime). KV-split x2 is exact (shift-free exp2 softmax): blocks
// write unnormalized bf16 O-partials + f32 l-partials (in qkv's unused V cols);
// k_ored combines. In-register P via permlane32/16_swap; Z4 C-operand init;
// XCD-pinned (h,b,split). Q pre-scaled by log2(e)/8 => p = exp2(sacc).
__global__ __launch_bounds__(128, 2) void k_attn(const unsigned short* __restrict__ qkv,
                                                 const unsigned short* __restrict__ vtg,
                                                 unsigned short* __restrict__ opart,
                                                 float* __restrict__ lout) {
    __shared__ unsigned short LDS[16384];          // 32 KB
    unsigned short* Qs = LDS;                      // [128][64] swizzled (dead after qf preload)
    unsigned short* Ks0 = LDS;                     // [2][64][64]  (overlays Qs)
    unsigned short* Vt0 = LDS + 8192;              // [2][64][64]  (rows=d, cols=k)

    const int t = threadIdx.x;                     // 0..127
    const int lane = t & 63, wave = t >> 6;        // wave in {0,1}
    const int l16 = lane & 15, quad = lane >> 4;
    const int l8 = l16 & 7;
    // XCD decode of 1024 blocks: same (h,b,split) -> same XCD
    const int id = blockIdx.x;
    const int xcd = id & 7, loc = id >> 3;         // loc 0..127
    const int qb = loc & 15;                       // q-block 0..15
    const int P = xcd + 8 * (loc >> 4);            // 0..63 = (h,b,split)
    const int h = P & 15, rest = P >> 4;
    const int b = rest & 1, split = rest >> 1;
    const int q0 = qb * 128;

    const unsigned short* qbase = qkv + (size_t)(b * 2048) * 3072 + h * 64;
    const unsigned short* kbase = qbase + 1024 + (size_t)(split * 1024) * 3072;
    const unsigned short* vtbase = vtg + (size_t)((b * 16 + h) * 64) * 2048 + split * 1024;

    // stage Q tile [128][64] swizzled (1024 16B-chunks / 128 threads = 8 each)
    #pragma unroll
    for (int i = 0; i < 8; ++i) {
        int B = i * 128 + t;
        int row = B >> 3, c = (B & 7) ^ (row & 7);
        gl_lds16(qbase + (size_t)(q0 + row) * 3072 + c * 8, &Qs[B * 8]);
    }

    // per-lane staging ptrs for K / Vt tiles (512 chunks / 128 threads = 4 each)
    const unsigned short* kp[4];
    const unsigned short* vp[4];
    #pragma unroll
    for (int i = 0; i < 4; ++i) {
        int B = i * 128 + t;
        int r = B >> 3, c = (B & 7) ^ (r & 7);
        kp[i] = kbase + (size_t)r * 3072 + c * 8;
        vp[i] = vtbase + (size_t)r * 2048 + c * 8;
    }

    __syncthreads();                               // Q staged & visible

    // preload Q B-fragments (loop-invariant): n = wave*64 + ni*16 + l16
    short8 qf[4][2];
    #pragma unroll
    for (int ni = 0; ni < 4; ++ni)
        #pragma unroll
        for (int kk = 0; kk < 2; ++kk)
            qf[ni][kk] = *(const short8*)&Qs[(wave * 64 + ni * 16 + l16) * 64 + ((kk * 4 + quad) ^ l8) * 8];

    __syncthreads();                               // all Qs reads done before K/V overwrite

    // prefetch tile 0 into buffer 0 (overwrites Qs region)
    #pragma unroll
    for (int i = 0; i < 4; ++i) {
        gl_lds16(kp[i], &Ks0[(i * 128 + t) * 8]);
        gl_lds16(vp[i], &Vt0[(i * 128 + t) * 8]);
        kp[i] += 64 * 3072; vp[i] += 64;
    }

    f32x4 acc_o[4][4];
    #pragma unroll
    for (int mo = 0; mo < 4; ++mo)
        #pragma unroll
        for (int nd = 0; nd < 4; ++nd) acc_o[mo][nd] = zero4();
    f32x4 acc_l[4] = {zero4(), zero4(), zero4(), zero4()};
    const f32x4 Z4 = zero4();                      // persistent zero C-operand
    short8 ones;
    #pragma unroll
    for (int i = 0; i < 8; ++i) ones[i] = (short)0x3F80;   // bf16 1.0

    __syncthreads();                               // tile 0 staged & visible

    for (int j = 0; j < 16; ++j) {
        const unsigned short* Ks = Ks0 + (j & 1) * 4096;
        const unsigned short* Vt = Vt0 + (j & 1) * 4096;

        // prefetch tile j+1 into the other buffer (overlaps this iter's compute)
        if (j < 15) {
            unsigned short* Kn = Ks0 + ((j + 1) & 1) * 4096;
            unsigned short* Vn = Vt0 + ((j + 1) & 1) * 4096;
            #pragma unroll
            for (int i = 0; i < 4; ++i) {
                gl_lds16(kp[i], &Kn[(i * 128 + t) * 8]);
                gl_lds16(vp[i], &Vn[(i * 128 + t) * 8]);
                kp[i] += 64 * 3072; vp[i] += 64;
            }
        }

        // S^T = K @ Q^T : per wave [64 k x 64 q], C-in = Z4 (no accvgpr zero-init)
        f32x4 sacc[4][4];
        #pragma unroll
        for (int mi = 0; mi < 4; ++mi) {
            short8 kf0 = *(const short8*)&Ks[(mi * 16 + l16) * 64 + ((0 + quad) ^ l8) * 8];
            short8 kf1 = *(const short8*)&Ks[(mi * 16 + l16) * 64 + ((4 + quad) ^ l8) * 8];
            #pragma unroll
            for (int ni = 0; ni < 4; ++ni) {
                sacc[mi][ni] = __builtin_amdgcn_mfma_f32_16x16x32_bf16(kf0, qf[ni][0], Z4, 0, 0, 0);
                sacc[mi][ni] = __builtin_amdgcn_mfma_f32_16x16x32_bf16(kf1, qf[ni][1], sacc[mi][ni], 0, 0, 0);
            }
        }

        // p = exp2(sacc), pack to bf16, redistribute IN-REGISTER to PV A-fragments.
        short8 pf[4][2];
        #pragma unroll
        for (int ni = 0; ni < 4; ++ni)
            #pragma unroll
            for (int kk = 0; kk < 2; ++kk) {
                float e00 = __builtin_amdgcn_exp2f(sacc[2 * kk][ni][0]);
                float e01 = __builtin_amdgcn_exp2f(sacc[2 * kk][ni][1]);
                float e02 = __builtin_amdgcn_exp2f(sacc[2 * kk][ni][2]);
                float e03 = __builtin_amdgcn_exp2f(sacc[2 * kk][ni][3]);
                float e10 = __builtin_amdgcn_exp2f(sacc[2 * kk + 1][ni][0]);
                float e11 = __builtin_amdgcn_exp2f(sacc[2 * kk + 1][ni][1]);
                float e12 = __builtin_amdgcn_exp2f(sacc[2 * kk + 1][ni][2]);
                float e13 = __builtin_amdgcn_exp2f(sacc[2 * kk + 1][ni][3]);
                unsigned int a0 = pack2bf(e00, e01);
                unsigned int b0 = pack2bf(e10, e11);
                unsigned int a1 = pack2bf(e02, e03);
                unsigned int b1 = pack2bf(e12, e13);
                asm volatile("v_permlane32_swap_b32 %0, %1\n\t"
                             "v_permlane16_swap_b32 %0, %1"
                             : "+v"(a0), "+v"(b0));
                asm volatile("v_permlane32_swap_b32 %0, %1\n\t"
                             "v_permlane16_swap_b32 %0, %1"
                             : "+v"(a1), "+v"(b1));
                union { unsigned int u[4]; short8 s; } cv;
                cv.u[0] = a0; cv.u[1] = a1; cv.u[2] = b0; cv.u[3] = b1;
                pf[ni][kk] = cv.s;
            }

        // PV + l: O[q][d] += P @ V, l[q] += P @ 1 (P entirely in registers)
        #pragma unroll
        for (int kk = 0; kk < 2; ++kk) {
            #pragma unroll
            for (int mo = 0; mo < 4; ++mo)
                acc_l[mo] = __builtin_amdgcn_mfma_f32_16x16x32_bf16(pf[mo][kk], ones, acc_l[mo], 0, 0, 0);
            #pragma unroll
            for (int nd = 0; nd < 4; ++nd) {
                short8 vf = *(const short8*)&Vt[(nd * 16 + l16) * 64 + ((kk * 4 + quad) ^ l8) * 8];
                #pragma unroll
                for (int mo = 0; mo < 4; ++mo)
                    acc_o[mo][nd] = __builtin_amdgcn_mfma_f32_16x16x32_bf16(pf[mo][kk], vf, acc_o[mo][nd], 0, 0, 0);
            }
        }

        __syncthreads();   // cur-tile reads done everywhere; drains prefetch
    }

    // epilogue: q = q0 + wave*64 + mo*16 + quad*4 + rr; unnormalized O + l partials
    const size_t obase = ((size_t)(split * 32 + b * 16 + h)) * 2048;
    #pragma unroll
    for (int mo = 0; mo < 4; ++mo)
        #pragma unroll
        for (int rr = 0; rr < 4; ++rr) {
            int qg = q0 + wave * 64 + mo * 16 + quad * 4 + rr;
            unsigned short* op = opart + (obase + qg) * 64;
            #pragma unroll
            for (int nd = 0; nd < 4; ++nd)
                op[nd * 16 + l16] = f2bf(acc_o[mo][nd][rr]);
            if (l16 == 0)
                lout[(size_t)(b * 2048 + qg) * 1536 + 1024 + split * 16 + h] = acc_l[mo][rr];
        }
}

// ---------- combine KV-split partials: obuf = (O0+O1)/(l0+l1), bf16 ----------
__global__ __launch_bounds__(256) void k_ored(const unsigned short* __restrict__ opart,
                                              const float* __restrict__ lin,
                                              unsigned short* __restrict__ o) {
    const int bid = blockIdx.x;                   // 4096 = 32 bh * 128 q-chunks
    const int bh = bid >> 7, chunk = bid & 127;
    const int t = threadIdx.x;
    const int qloc = t >> 4, dd = (t & 15) * 4;
    const int q = chunk * 16 + qloc;
    const int b = bh >> 4, h = bh & 15;
    const size_t i0 = ((size_t)bh * 2048 + q) * 64 + dd;
    const size_t i1 = ((size_t)(32 + bh) * 2048 + q) * 64 + dd;
    uint2 p0 = *(const uint2*)(opart + i0);
    uint2 p1 = *(const uint2*)(opart + i1);
    const size_t lrow = (size_t)(b * 2048 + q) * 1536 + 1024;
    float inv = 1.0f / (lin[lrow + h] + lin[lrow + 16 + h]);
    union { uint2 w; unsigned short u[4]; } a, c;
    a.w = p0;
    union { uint2 w; unsigned short u[4]; } bb; bb.w = p1;
    #pragma unroll
    for (int i = 0; i < 4; ++i)
        c.u[i] = f2bf((bf2f(a.u[i]) + bf2f(bb.u[i])) * inv);
    *(uint2*)(o + ((size_t)(b * 2048 + q)) * 1024 + h * 64 + dd) = c.w;
}

// ---------- LayerNorm (fused K-split combine): x = y + bf(res0) + bf(res1) ----------
// one row per WAVE, shuffle-only reduction
__global__ __launch_bounds__(256) void k_ln(const float* __restrict__ y,
                                            const unsigned short* __restrict__ p0,
                                            const unsigned short* __restrict__ p1,
                                            const float* __restrict__ g,
                                            const float* __restrict__ be,
                                            float* __restrict__ out) {
    const int row = blockIdx.x * 4 + (threadIdx.x >> 6);
    const int lane = threadIdx.x & 63;
    const float* xr = y + (size_t)row * 1024;
    const unsigned short* ar = p0 + (size_t)row * 1024;
    const unsigned short* br = p1 + (size_t)row * 1024;
    float4 v[4];
    float s = 0.f, sq = 0.f;
    #pragma unroll
    for (int i = 0; i < 4; ++i) {
        float4 vy = *(const float4*)(xr + i * 256 + lane * 4);
        union { uint2 w; unsigned short u[4]; } ua, ub;
        ua.w = *(const uint2*)(ar + i * 256 + lane * 4);
        ub.w = *(const uint2*)(br + i * 256 + lane * 4);
        v[i].x = vy.x + bf2f(ua.u[0]) + bf2f(ub.u[0]);
        v[i].y = vy.y + bf2f(ua.u[1]) + bf2f(ub.u[1]);
        v[i].z = vy.z + bf2f(ua.u[2]) + bf2f(ub.u[2]);
        v[i].w = vy.w + bf2f(ua.u[3]) + bf2f(ub.u[3]);
        s  += v[i].x + v[i].y + v[i].z + v[i].w;
        sq += v[i].x * v[i].x + v[i].y * v[i].y + v[i].z * v[i].z + v[i].w * v[i].w;
    }
    #pragma unroll
    for (int off = 32; off; off >>= 1) { s += __shfl_down(s, off); sq += __shfl_down(sq, off); }
    s = __shfl(s, 0); sq = __shfl(sq, 0);
    float mu = s * (1.f / 1024.f);
    float var = sq * (1.f / 1024.f) - mu * mu;
    float rstd = rsqrtf(var + 1e-6f);
    float* orow = out + (size_t)row * 1024;
    #pragma unroll
    for (int i = 0; i < 4; ++i) {
        float4 gg = *(const float4*)(g + i * 256 + lane * 4);
        float4 bb = *(const float4*)(be + i * 256 + lane * 4);
        float4 ov;
        ov.x = (v[i].x - mu) * rstd * gg.x + bb.x;
        ov.y = (v[i].y - mu) * rstd * gg.y + bb.y;
        ov.z = (v[i].z - mu) * rstd * gg.z + bb.z;
        ov.w = (v[i].w - mu) * rstd * gg.w + bb.w;
        *(float4*)(orow + i * 256 + lane * 4) = ov;
    }
}

// ---------- launch ----------
extern "C" void kernel_launch(void* const* d_in, const int* in_sizes, int n_in,
                              void* d_out, int out_size, void* d_ws, size_t ws_size,
                              hipStream_t stream) {
    (void)in_sizes; (void)n_in; (void)out_size; (void)ws_size;
    const float* y    = (const float*)d_in[0];
    const float* Wqkv = (const float*)d_in[1];
    const float* bqkv = (const float*)d_in[2];
    const float* Wmsa = (const float*)d_in[3];
    const float* Bq = (const float*)d_in[4];
    const float* Aq = (const float*)d_in[5];
    const float* Bk = (const float*)d_in[6];
    const float* Ak = (const float*)d_in[7];
    const float* Bv = (const float*)d_in[8];
    const float* Av = (const float*)d_in[9];
    const float* Bo = (const float*)d_in[10];
    const float* Ao = (const float*)d_in[11];
    const float* gamma = (const float*)d_in[12];
    const float* beta  = (const float*)d_in[13];

    char* ws = (char*)d_ws;
    unsigned short* yb   = (unsigned short*)(ws);               // 8 MB bf16(y); reused as obuf
    unsigned short* weq  = (unsigned short*)(ws + (8u  << 20)); // 6 MB [3072][1024], wem contiguous after
    unsigned short* qkv  = (unsigned short*)(ws + (16u << 20)); // 24 MB [4096][3072] (V cols hold l-partials); reused as res
    unsigned short* vtg  = (unsigned short*)(ws + (40u << 20)); // 8 MB [32][64][2048] V^T
    unsigned short* opart= (unsigned short*)(ws + (48u << 20)); // 16 MB [2][32][2048][64] bf16 O-partials
    unsigned short* wem  = weq + 3145728;                       // 2 MB [1024][1024]
    unsigned short* obuf = yb;
    unsigned short* resb = qkv;                                 // [2][4096][1024] bf16 partials (after k_ored)

    k_prep<<<17408, 256, 0, stream>>>(y, Wqkv, Wmsa, Bq, Aq, Bk, Ak, Bv, Av, Bo, Ao, weq, yb);
    k_gemm<128, 0, 3, 1><<<768, 256, 0, stream>>>(yb, weq, bqkv, nullptr, vtg, (void*)qkv, 4096, 3072, 1024, 1024);
    k_attn<<<1024, 128, 0, stream>>>(qkv, vtg, opart, (float*)qkv);
    k_ored<<<4096, 256, 0, stream>>>(opart, (const float*)qkv, obuf);
    k_gemm<128, 2, 3, 2><<<512, 256, 0, stream>>>(obuf, wem, nullptr, nullptr, nullptr, (void*)resb, 4096, 1024, 512, 1024);
    k_ln  <<<1024, 256, 0, stream>>>(y, resb, resb + 4194304, gamma, beta, (float*)d_out);
}

// Round 12
// 207.345 us; speedup vs baseline: 1.0322x; 1.0322x over previous
//
#include <hip/hip_runtime.h>
#include <hip/hip_bf16.h>
#include <stdint.h>

// ---------- types ----------
typedef __attribute__((ext_vector_type(8))) short short8;   // 8 x bf16 (raw)
typedef __attribute__((ext_vector_type(4))) float f32x4;

typedef const __attribute__((address_space(1))) void gv_t;
typedef __attribute__((address_space(3))) void lv_t;

#define SCQ 0.18033688011112042f   // log2(e)/sqrt(64), folded into Q projection

__device__ __forceinline__ void gl_lds16(const void* g, void* l) {
    // async global->LDS, 16B per lane; LDS dest must be waveBase + lane*16
    __builtin_amdgcn_global_load_lds((gv_t*)g, (lv_t*)l, 16, 0, 0);
}

__device__ __forceinline__ unsigned short f2bf(float f) {
    union { float f; unsigned int u; } v; v.f = f;
    unsigned int r = v.u + 0x7fffu + ((v.u >> 16) & 1u);   // RNE
    return (unsigned short)(r >> 16);
}

__device__ __forceinline__ float bf2f(unsigned short u) {
    union { unsigned int i; float f; } v; v.i = ((unsigned int)u) << 16; return v.f;
}

__device__ __forceinline__ unsigned int pack2bf(float a, float b) {
    union { __hip_bfloat162 h2; unsigned int u; } cv;
    cv.h2 = __float22bfloat162_rn(make_float2(a, b));   // v_cvt_pk_bf16_f32 on gfx950
    return cv.u;                                        // low = a, high = b
}

__device__ __forceinline__ f32x4 zero4() { f32x4 z = {0.f, 0.f, 0.f, 0.f}; return z; }

// ---------- fused prep: LoRA weight fold (Wqkv & Wmsa) + y->bf16 cvt ----------
__global__ void k_prep(const float* __restrict__ y,
                       const float* __restrict__ Wqkv, const float* __restrict__ Wmsa,
                       const float* __restrict__ Bq, const float* __restrict__ Aq,
                       const float* __restrict__ Bk, const float* __restrict__ Ak,
                       const float* __restrict__ Bv, const float* __restrict__ Av,
                       const float* __restrict__ Bo, const float* __restrict__ Ao,
                       unsigned short* __restrict__ wout, unsigned short* __restrict__ yb) {
    const int bid = blockIdx.x;
    if (bid < 16384) {
        int idx = bid * 256 + threadIdx.x;     // n*1024 + k, n in [0,4096)
        int n = idx >> 10, k = idx & 1023;
        int sel = n >> 10, n0 = n & 1023;
        const float* Bp = (sel == 0) ? Bq : (sel == 1) ? Bk : (sel == 2) ? Bv : Bo;
        const float* Ap = (sel == 0) ? Aq : (sel == 1) ? Ak : (sel == 2) ? Av : Ao;
        float acc = (sel < 3) ? Wqkv[idx] : Wmsa[idx - 3145728];
        // B row is 8 contiguous floats -> 2x float4 (was 8 scalar loads)
        float4 b0 = *(const float4*)(Bp + k * 8);
        float4 b1 = *(const float4*)(Bp + k * 8 + 4);
        acc += b0.x * Ap[0 * 1024 + n0] + b0.y * Ap[1 * 1024 + n0]
             + b0.z * Ap[2 * 1024 + n0] + b0.w * Ap[3 * 1024 + n0]
             + b1.x * Ap[4 * 1024 + n0] + b1.y * Ap[5 * 1024 + n0]
             + b1.z * Ap[6 * 1024 + n0] + b1.w * Ap[7 * 1024 + n0];
        wout[idx] = f2bf(acc * ((sel == 0) ? SCQ : 1.0f));
    } else {
        int i = ((bid - 16384) * 256 + threadIdx.x) * 4;
        float4 v = *(const float4*)(y + i);
        union { unsigned short u[4]; uint2 w; } o;
        o.u[0] = f2bf(v.x); o.u[1] = f2bf(v.y); o.u[2] = f2bf(v.z); o.u[3] = f2bf(v.w);
        *(uint2*)(yb + i) = o.w;
    }
}

// ---------- GEMM: C[M,N] = A[M,K](bf16) @ B[N,K]^T(bf16), dbuf cross-barrier prefetch ----------
// EPI=0: bf16(acc+bias[col]); cols<1024 get SCQ on bias; cols>=2048 (V) are written
//        TRANSPOSED into vtg[b,h][d][tok] via LDS -> coalesced 128B global stores.
// EPI=2: bf16(acc) partial into Cout + split*4096*1024  (K-split x2; k_ln combines).
// XMAP=1 (gemm1): each XCD owns an 8y x 12x group. XMAP=2 (gemm2 K-split).
template <int TM, int EPI, int MINW, int XMAP>
__global__ __launch_bounds__(256, MINW) void k_gemm(const unsigned short* __restrict__ Ag,
                                                    const unsigned short* __restrict__ Bg,
                                                    const float* __restrict__ bias,
                                                    const float* __restrict__ yres,
                                                    unsigned short* __restrict__ vtg,
                                                    void* __restrict__ Cout,
                                                    int M, int N, int K, int Kst) {
    constexpr int WAVES_N = 256 / TM;
    constexpr int WN = TM / 2;
    constexpr int NI = WN / 16;
    constexpr int ACALLS = TM / 64;
    constexpr int ASZ = 2 * TM * 32;               // shorts
    __shared__ unsigned short SH[ASZ + 2 * 128 * 32];
    unsigned short* As0 = SH;                      // [2][TM*32]
    unsigned short* Bs0 = SH + ASZ;                // [2][128*32]
    const int flat = threadIdx.x;
    int m0, n0, koff = 0, split = 0;
    if constexpr (XMAP == 1) {                     // 24 x-blocks, 32 y-blocks
        int id = blockIdx.x, xcd = id & 7, j = id >> 3;
        int yy = (xcd & 3) * 8 + j / 12;
        int xx = (xcd >> 2) * 12 + j % 12;
        m0 = yy * TM; n0 = xx * 128;
    } else if constexpr (XMAP == 2) {              // K-split x2: 8 x-blocks, 32 y-blocks, 2 splits
        int id = blockIdx.x, xcd = id & 7, j = id >> 3;   // j in [0,64)
        split = xcd >> 2;
        int yy = (xcd & 3) * 8 + (j >> 3);         // [0,32)
        int xx = j & 7;                            // [0,8)
        m0 = yy * TM; n0 = xx * 128; koff = split * 512;
    } else {
        m0 = blockIdx.y * TM; n0 = blockIdx.x * 128;
    }
    const int lane = flat & 63, wave = flat >> 6;
    const int l16 = lane & 15, quad = lane >> 4;
    const int wm = (wave / WAVES_N) * 64, wn = (wave % WAVES_N) * WN;

    f32x4 acc[4][NI];
    #pragma unroll
    for (int mi = 0; mi < 4; ++mi)
        #pragma unroll
        for (int ni = 0; ni < NI; ++ni) acc[mi][ni] = zero4();

    const unsigned short* ap = Ag + (size_t)(m0 + (flat >> 2)) * Kst + koff + (flat & 3) * 8;
    const unsigned short* bp = Bg + (size_t)(n0 + (flat >> 2)) * Kst + koff + (flat & 3) * 8;
    const size_t rstep = (size_t)64 * Kst;

    #pragma unroll
    for (int c = 0; c < ACALLS; ++c) gl_lds16(ap + c * rstep, &As0[c * 2048 + flat * 8]);
    gl_lds16(bp,         &Bs0[flat * 8]);
    gl_lds16(bp + rstep, &Bs0[2048 + flat * 8]);
    ap += 32; bp += 32;
    __syncthreads();

    for (int k0 = 0; k0 < K; k0 += 32) {
        const int cur = (k0 >> 5) & 1;
        if (k0 + 32 < K) {
            const int nxt = cur ^ 1;
            #pragma unroll
            for (int c = 0; c < ACALLS; ++c) gl_lds16(ap + c * rstep, &As0[nxt * TM * 32 + c * 2048 + flat * 8]);
            gl_lds16(bp,         &Bs0[nxt * 4096 + flat * 8]);
            gl_lds16(bp + rstep, &Bs0[nxt * 4096 + 2048 + flat * 8]);
            ap += 32; bp += 32;
        }

        short8 af[4], bfr[NI];
        #pragma unroll
        for (int i = 0; i < 4; ++i) af[i] = *(const short8*)&As0[cur * TM * 32 + (wm + i * 16 + l16) * 32 + quad * 8];
        #pragma unroll
        for (int i = 0; i < NI; ++i) bfr[i] = *(const short8*)&Bs0[cur * 4096 + (wn + i * 16 + l16) * 32 + quad * 8];
        #pragma unroll
        for (int mi = 0; mi < 4; ++mi)
            #pragma unroll
            for (int ni = 0; ni < NI; ++ni)
                acc[mi][ni] = __builtin_amdgcn_mfma_f32_16x16x32_bf16(af[mi], bfr[ni], acc[mi][ni], 0, 0, 0);

        __syncthreads();
    }

    // epilogue: C/D layout col=lane&15, row=quad*4+reg
    if constexpr (EPI == 0) {
        unsigned short* C = (unsigned short*)Cout;
        if (n0 < 2048) {      // Q/K columns: normal row-major bf16 store
            #pragma unroll
            for (int ni = 0; ni < NI; ++ni) {
                int col = n0 + wn + ni * 16 + l16;
                float bv = bias[col] * ((col < 1024) ? SCQ : 1.0f);
                #pragma unroll
                for (int mi = 0; mi < 4; ++mi) {
                    int row = m0 + wm + mi * 16 + quad * 4;
                    #pragma unroll
                    for (int r = 0; r < 4; ++r)
                        C[(size_t)(row + r) * N + col] = f2bf(acc[mi][ni][r] + bv);
                }
            }
        } else {              // V columns: LDS transpose -> coalesced vtg[(b,h,d)][tok] stores
            if constexpr (TM == 128) {
                #pragma unroll
                for (int ni = 0; ni < NI; ++ni) {
                    int c = wn + ni * 16 + l16;
                    float bv = bias[n0 + c];
                    int sw = (c & 7) << 3;
                    #pragma unroll
                    for (int mi = 0; mi < 4; ++mi) {
                        int row = wm + mi * 16 + quad * 4;
                        uint2 w;
                        w.x = pack2bf(acc[mi][ni][0] + bv, acc[mi][ni][1] + bv);
                        w.y = pack2bf(acc[mi][ni][2] + bv, acc[mi][ni][3] + bv);
                        *(uint2*)&SH[c * 128 + (row ^ sw)] = w;
                    }
                }
                __syncthreads();
                const int bb = m0 >> 11, ss = m0 & 2047;
                #pragma unroll
                for (int p = 0; p < 4; ++p) {
                    int c = p * 32 + (flat >> 3);
                    int col = n0 + c;
                    int hh = (col - 2048) >> 6, dd = col & 63;
                    unsigned short* dst = vtg + (size_t)(hh * 64 + dd) * 2048
                                              + (size_t)bb * 2097152 + ss;
                    int sw = (c & 7) << 3;
                    #pragma unroll
                    for (int hf = 0; hf < 2; ++hf) {
                        int off = hf * 64 + (flat & 7) * 8;
                        uint4 v = *(const uint4*)&SH[c * 128 + (off ^ sw)];
                        *(uint4*)(dst + off) = v;
                    }
                }
            }
        }
    } else {   // EPI == 2: bf16 K-split partial
        unsigned short* C = (unsigned short*)Cout + (size_t)split * 4194304;   // 4096*1024
        #pragma unroll
        for (int ni = 0; ni < NI; ++ni) {
            int col = n0 + wn + ni * 16 + l16;
            #pragma unroll
            for (int mi = 0; mi < 4; ++mi) {
                int row = m0 + wm + mi * 16 + quad * 4;
                #pragma unroll
                for (int r = 0; r < 4; ++r)
                    C[(size_t)(row + r) * N + col] = f2bf(acc[mi][ni][r]);
            }
        }
    }
}

// ---------- fused flash attention (q-tile 128, 4 waves x 32 q/wave, NO KV-split) ----------
// r10 best-total config (208.0us) + T5 setprio: the two waves sharing a SIMD come
// from DIFFERENT blocks (block wave-i -> SIMD i; 2 blocks/CU), so they run at
// independent phases -> s_setprio(1) around the MFMA clusters lets the matrix-pipe
// wave preempt the other block's staging/softmax VALU issue (m191 mechanism:
// +4-7% attn; null only for lockstep waves). Everything else identical to r10:
// in-register P (permlane32/16_swap), Qs-overlay (32KB LDS), Z4 C-operand init,
// in-kernel softmax normalization, XCD-aware block remap (FETCH 69.7 -> 12.3 MB).
__global__ __launch_bounds__(256, 2) void k_attn(const unsigned short* __restrict__ qkv,
                                                 const unsigned short* __restrict__ vtg,
                                                 unsigned short* __restrict__ o) {
    __shared__ unsigned short LDS[16384];          // 32 KB
    unsigned short* Qs = LDS;                      // [128][64] swizzled (dead after qf preload)
    unsigned short* Ks0 = LDS;                     // [2][64][64]  (overlays Qs)
    unsigned short* Vt0 = LDS + 8192;              // [2][64][64]  (rows=d, cols=k)

    const int t = threadIdx.x;
    const int lane = t & 63, wave = t >> 6;
    const int l16 = lane & 15, quad = lane >> 4;
    const int l8 = l16 & 7;
    // XCD-aware decode of flat block id (512 blocks): same (h,b) -> same XCD
    const int id = blockIdx.x;
    const int xcd = id & 7, loc = id >> 3;
    const int qb = loc & 15;                       // q-block 0..15
    const int P = xcd + 8 * (loc >> 4);            // (h,b) pair 0..31
    const int h = P & 15, b = P >> 4;
    const int q0 = qb * 128;

    const unsigned short* qbase = qkv + (size_t)(b * 2048) * 3072 + h * 64;
    const unsigned short* kbase = qbase + 1024;
    const unsigned short* vtbase = vtg + (size_t)((b * 16 + h) * 64) * 2048;

    // stage Q tile [128][64] swizzled (1024 16B-chunks / 256 threads = 4 each)
    #pragma unroll
    for (int i = 0; i < 4; ++i) {
        int B = i * 256 + t;                       // 16B-block index 0..1023
        int row = B >> 3, c = (B & 7) ^ (row & 7);
        gl_lds16(qbase + (size_t)(q0 + row) * 3072 + c * 8, &Qs[B * 8]);
    }

    // per-lane staging constants for K / Vt tiles (512 chunks each)
    const int B0 = t, B1 = t + 256;
    const int r0 = B0 >> 3, c0 = (B0 & 7) ^ (r0 & 7);
    const int r1 = B1 >> 3, c1 = (B1 & 7) ^ (r1 & 7);
    const unsigned short* kp0 = kbase + (size_t)r0 * 3072 + c0 * 8;
    const unsigned short* kp1 = kbase + (size_t)r1 * 3072 + c1 * 8;
    const unsigned short* vp0 = vtbase + (size_t)r0 * 2048 + c0 * 8;
    const unsigned short* vp1 = vtbase + (size_t)r1 * 2048 + c1 * 8;

    __syncthreads();                               // Q staged & visible

    // preload Q B-fragments (loop-invariant): B[n=q][k=d], n = wave*32 + ni*16 + l16
    short8 qf[2][2];
    #pragma unroll
    for (int ni = 0; ni < 2; ++ni)
        #pragma unroll
        for (int kk = 0; kk < 2; ++kk)
            qf[ni][kk] = *(const short8*)&Qs[(wave * 32 + ni * 16 + l16) * 64 + ((kk * 4 + quad) ^ l8) * 8];

    __syncthreads();                               // all Qs reads done before K/V overwrite

    // prefetch tile 0 into buffer 0 (overwrites Qs region)
    gl_lds16(kp0, &Ks0[B0 * 8]);
    gl_lds16(kp1, &Ks0[B1 * 8]);
    gl_lds16(vp0, &Vt0[B0 * 8]);
    gl_lds16(vp1, &Vt0[B1 * 8]);
    kp0 += 64 * 3072; kp1 += 64 * 3072; vp0 += 64; vp1 += 64;

    f32x4 acc_o[2][4];
    #pragma unroll
    for (int mo = 0; mo < 2; ++mo)
        #pragma unroll
        for (int nd = 0; nd < 4; ++nd) acc_o[mo][nd] = zero4();
    f32x4 acc_l[2] = {zero4(), zero4()};
    const f32x4 Z4 = zero4();                      // persistent zero C-operand
    short8 ones;
    #pragma unroll
    for (int i = 0; i < 8; ++i) ones[i] = (short)0x3F80;   // bf16 1.0

    __syncthreads();                               // tile 0 staged & visible

    for (int j = 0; j < 32; ++j) {
        const unsigned short* Ks = Ks0 + (j & 1) * 4096;
        const unsigned short* Vt = Vt0 + (j & 1) * 4096;

        // prefetch tile j+1 into the other buffer (overlaps this iter's compute)
        if (j < 31) {
            unsigned short* Kn = Ks0 + ((j + 1) & 1) * 4096;
            unsigned short* Vn = Vt0 + ((j + 1) & 1) * 4096;
            gl_lds16(kp0, &Kn[B0 * 8]);
            gl_lds16(kp1, &Kn[B1 * 8]);
            gl_lds16(vp0, &Vn[B0 * 8]);
            gl_lds16(vp1, &Vn[B1 * 8]);
            kp0 += 64 * 3072; kp1 += 64 * 3072; vp0 += 64; vp1 += 64;
        }

        // S^T = K @ Q^T : per wave [64 k x 32 q], C-in = Z4 (no accvgpr zero-init)
        f32x4 sacc[4][2];
        __builtin_amdgcn_s_setprio(1);             // T5: favor MFMA wave over co-resident block's wave
        #pragma unroll
        for (int mi = 0; mi < 4; ++mi) {
            short8 kf0 = *(const short8*)&Ks[(mi * 16 + l16) * 64 + ((0 + quad) ^ l8) * 8];
            short8 kf1 = *(const short8*)&Ks[(mi * 16 + l16) * 64 + ((4 + quad) ^ l8) * 8];
            #pragma unroll
            for (int ni = 0; ni < 2; ++ni) {
                sacc[mi][ni] = __builtin_amdgcn_mfma_f32_16x16x32_bf16(kf0, qf[ni][0], Z4, 0, 0, 0);
                sacc[mi][ni] = __builtin_amdgcn_mfma_f32_16x16x32_bf16(kf1, qf[ni][1], sacc[mi][ni], 0, 0, 0);
            }
        }
        __builtin_amdgcn_s_setprio(0);

        // p = exp2(sacc), pack to bf16, redistribute IN-REGISTER to PV A-fragments.
        // sacc layout: lane(l16,quad) holds P(q=ni*16+l16, k=mi*16+quad*4+r).
        // target pf[ni][kk]: lane holds P(q=ni*16+l16, k=kk*32+quad*8+j'), j'=0..7.
        short8 pf[2][2];
        #pragma unroll
        for (int ni = 0; ni < 2; ++ni)
            #pragma unroll
            for (int kk = 0; kk < 2; ++kk) {
                float e00 = __builtin_amdgcn_exp2f(sacc[2 * kk][ni][0]);
                float e01 = __builtin_amdgcn_exp2f(sacc[2 * kk][ni][1]);
                float e02 = __builtin_amdgcn_exp2f(sacc[2 * kk][ni][2]);
                float e03 = __builtin_amdgcn_exp2f(sacc[2 * kk][ni][3]);
                float e10 = __builtin_amdgcn_exp2f(sacc[2 * kk + 1][ni][0]);
                float e11 = __builtin_amdgcn_exp2f(sacc[2 * kk + 1][ni][1]);
                float e12 = __builtin_amdgcn_exp2f(sacc[2 * kk + 1][ni][2]);
                float e13 = __builtin_amdgcn_exp2f(sacc[2 * kk + 1][ni][3]);
                unsigned int a0 = pack2bf(e00, e01);   // rows 0-1 of mi=2kk
                unsigned int b0 = pack2bf(e10, e11);   // rows 0-1 of mi=2kk+1
                unsigned int a1 = pack2bf(e02, e03);   // rows 2-3 of mi=2kk
                unsigned int b1 = pack2bf(e12, e13);   // rows 2-3 of mi=2kk+1
                asm volatile("v_permlane32_swap_b32 %0, %1\n\t"
                             "v_permlane16_swap_b32 %0, %1"
                             : "+v"(a0), "+v"(b0));
                asm volatile("v_permlane32_swap_b32 %0, %1\n\t"
                             "v_permlane16_swap_b32 %0, %1"
                             : "+v"(a1), "+v"(b1));
                union { unsigned int u[4]; short8 s; } cv;
                cv.u[0] = a0; cv.u[1] = a1; cv.u[2] = b0; cv.u[3] = b1;
                pf[ni][kk] = cv.s;
            }

        // PV + l: O[q][d] += P @ V, l[q] += P @ 1 (P entirely in registers)
        __builtin_amdgcn_s_setprio(1);
        #pragma unroll
        for (int kk = 0; kk < 2; ++kk) {
            #pragma unroll
            for (int mo = 0; mo < 2; ++mo)
                acc_l[mo] = __builtin_amdgcn_mfma_f32_16x16x32_bf16(pf[mo][kk], ones, acc_l[mo], 0, 0, 0);
            #pragma unroll
            for (int nd = 0; nd < 4; ++nd) {
                short8 vf = *(const short8*)&Vt[(nd * 16 + l16) * 64 + ((kk * 4 + quad) ^ l8) * 8];
                #pragma unroll
                for (int mo = 0; mo < 2; ++mo)
                    acc_o[mo][nd] = __builtin_amdgcn_mfma_f32_16x16x32_bf16(pf[mo][kk], vf, acc_o[mo][nd], 0, 0, 0);
            }
        }
        __builtin_amdgcn_s_setprio(0);

        __syncthreads();   // cur-tile reads done everywhere; drains prefetch
    }

    // epilogue: lane holds rows q = q0 + wave*32 + mo*16 + quad*4 + rr; acc_l[mo][rr] is l
    #pragma unroll
    for (int mo = 0; mo < 2; ++mo)
        #pragma unroll
        for (int rr = 0; rr < 4; ++rr) {
            float inv = 1.0f / acc_l[mo][rr];
            int qg = q0 + wave * 32 + mo * 16 + quad * 4 + rr;
            size_t base = ((size_t)(b * 2048 + qg)) * 1024 + h * 64;
            #pragma unroll
            for (int nd = 0; nd < 4; ++nd)
                o[base + nd * 16 + l16] = f2bf(acc_o[mo][nd][rr] * inv);
        }
}

// ---------- LayerNorm (fused K-split combine): x = y + bf(res0) + bf(res1) ----------
// one row per WAVE, shuffle-only reduction
__global__ __launch_bounds__(256) void k_ln(const float* __restrict__ y,
                                            const unsigned short* __restrict__ p0,
                                            const unsigned short* __restrict__ p1,
                                            const float* __restrict__ g,
                                            const float* __restrict__ be,
                                            float* __restrict__ out) {
    const int row = blockIdx.x * 4 + (threadIdx.x >> 6);
    const int lane = threadIdx.x & 63;
    const float* xr = y + (size_t)row * 1024;
    const unsigned short* ar = p0 + (size_t)row * 1024;
    const unsigned short* br = p1 + (size_t)row * 1024;
    float4 v[4];
    float s = 0.f, sq = 0.f;
    #pragma unroll
    for (int i = 0; i < 4; ++i) {
        float4 vy = *(const float4*)(xr + i * 256 + lane * 4);
        union { uint2 w; unsigned short u[4]; } ua, ub;
        ua.w = *(const uint2*)(ar + i * 256 + lane * 4);
        ub.w = *(const uint2*)(br + i * 256 + lane * 4);
        v[i].x = vy.x + bf2f(ua.u[0]) + bf2f(ub.u[0]);
        v[i].y = vy.y + bf2f(ua.u[1]) + bf2f(ub.u[1]);
        v[i].z = vy.z + bf2f(ua.u[2]) + bf2f(ub.u[2]);
        v[i].w = vy.w + bf2f(ua.u[3]) + bf2f(ub.u[3]);
        s  += v[i].x + v[i].y + v[i].z + v[i].w;
        sq += v[i].x * v[i].x + v[i].y * v[i].y + v[i].z * v[i].z + v[i].w * v[i].w;
    }
    #pragma unroll
    for (int off = 32; off; off >>= 1) { s += __shfl_down(s, off); sq += __shfl_down(sq, off); }
    s = __shfl(s, 0); sq = __shfl(sq, 0);
    float mu = s * (1.f / 1024.f);
    float var = sq * (1.f / 1024.f) - mu * mu;
    float rstd = rsqrtf(var + 1e-6f);
    float* orow = out + (size_t)row * 1024;
    #pragma unroll
    for (int i = 0; i < 4; ++i) {
        float4 gg = *(const float4*)(g + i * 256 + lane * 4);
        float4 bb = *(const float4*)(be + i * 256 + lane * 4);
        float4 ov;
        ov.x = (v[i].x - mu) * rstd * gg.x + bb.x;
        ov.y = (v[i].y - mu) * rstd * gg.y + bb.y;
        ov.z = (v[i].z - mu) * rstd * gg.z + bb.z;
        ov.w = (v[i].w - mu) * rstd * gg.w + bb.w;
        *(float4*)(orow + i * 256 + lane * 4) = ov;
    }
}

// ---------- launch ----------
extern "C" void kernel_launch(void* const* d_in, const int* in_sizes, int n_in,
                              void* d_out, int out_size, void* d_ws, size_t ws_size,
                              hipStream_t stream) {
    (void)in_sizes; (void)n_in; (void)out_size; (void)ws_size;
    const float* y    = (const float*)d_in[0];
    const float* Wqkv = (const float*)d_in[1];
    const float* bqkv = (const float*)d_in[2];
    const float* Wmsa = (const float*)d_in[3];
    const float* Bq = (const float*)d_in[4];
    const float* Aq = (const float*)d_in[5];
    const float* Bk = (const float*)d_in[6];
    const float* Ak = (const float*)d_in[7];
    const float* Bv = (const float*)d_in[8];
    const float* Av = (const float*)d_in[9];
    const float* Bo = (const float*)d_in[10];
    const float* Ao = (const float*)d_in[11];
    const float* gamma = (const float*)d_in[12];
    const float* beta  = (const float*)d_in[13];

    char* ws = (char*)d_ws;
    unsigned short* yb   = (unsigned short*)(ws);               // 8 MB bf16(y); reused as obuf
    unsigned short* weq  = (unsigned short*)(ws + (8u  << 20)); // 6 MB [3072][1024], wem contiguous after
    unsigned short* qkv  = (unsigned short*)(ws + (16u << 20)); // 24 MB [4096][3072]; reused as bf16 res0/res1
    unsigned short* vtg  = (unsigned short*)(ws + (40u << 20)); // 8 MB [32][64][2048] V^T
    unsigned short* wem  = weq + 3145728;                       // 2 MB [1024][1024]
    unsigned short* obuf = yb;
    unsigned short* resb = qkv;                                 // [2][4096][1024] bf16 partials

    k_prep<<<17408, 256, 0, stream>>>(y, Wqkv, Wmsa, Bq, Aq, Bk, Ak, Bv, Av, Bo, Ao, weq, yb);
    k_gemm<128, 0, 3, 1><<<768, 256, 0, stream>>>(yb, weq, bqkv, nullptr, vtg, (void*)qkv, 4096, 3072, 1024, 1024);
    k_attn<<<512, 256, 0, stream>>>(qkv, vtg, obuf);
    k_gemm<128, 2, 3, 2><<<512, 256, 0, stream>>>(obuf, wem, nullptr, nullptr, nullptr, (void*)resb, 4096, 1024, 512, 1024);
    k_ln  <<<1024, 256, 0, stream>>>(y, resb, resb + 4194304, gamma, beta, (float*)d_out);
}